// Round 1
// baseline (297.493 us; speedup 1.0000x reference)
//
#include <hip/hip_runtime.h>
#include <math.h>

// Problem constants
#define NB 8
#define LN 4096       // sequence length L
#define NH 8
#define NE 64
#define NC 512        // NH*NE channels
#define NM 64         // modes kept
#define LMASK 4095

// ws layout (in floats):
//  ft : float2[4096]                      @ 0        (32 KB)
//  Xp : float2[2][NB][NH][NE][NM]         @ 8192     (4 MB)   partial DFT sums (l-split 2)
//  OF : float2[NB][NM][NC]                @ 8192+1048576 (2 MB) scaled mixed spectrum
#define WS_FT 0
#define WS_XP 8192
#define WS_OF (8192 + 1048576)

__global__ void k_twiddle(float2* __restrict__ ft) {
    int j = blockIdx.x * blockDim.x + threadIdx.x;
    if (j < LN) {
        double a = (2.0 * M_PI / (double)LN) * (double)j;
        ft[j] = make_float2((float)cos(a), (float)sin(a));
    }
}

// Stage 1: partial forward DFT. grid (4 = mb2*ls2, NH, NB), block 512.
// thread: i = tx&63 (E_in), mg = tx>>6 (8 mode-groups of 4 modes)
__global__ __launch_bounds__(512) void k_stage1(const float* __restrict__ q,
                                                const float2* __restrict__ ftg,
                                                float2* __restrict__ Xp) {
    __shared__ float2 lft[LN];
    for (int j = threadIdx.x; j < LN; j += 512) lft[j] = ftg[j];
    __syncthreads();

    const int mb = blockIdx.x & 1;          // mode half (0..1)
    const int ls = blockIdx.x >> 1;         // l-split (0..1)
    const int h  = blockIdx.y;
    const int b  = blockIdx.z;
    const int i  = threadIdx.x & 63;
    const int mg = threadIdx.x >> 6;        // 0..7
    const int m0 = mb * 32 + mg * 4;        // first of 4 modes for this thread
    const int l0 = ls * 2048;

    float xr[4] = {0.f, 0.f, 0.f, 0.f};
    float xi[4] = {0.f, 0.f, 0.f, 0.f};

    const float* qb = q + ((size_t)b * LN + l0) * NC + h * 64 + i;
    int base = (m0 * l0) & LMASK;           // (m0*l) mod 4096, incremental

    for (int ll = 0; ll < 2048; ++ll) {
        const int l = l0 + ll;
        const float qv = qb[(size_t)ll * NC];
        int idx = base;
        #pragma unroll
        for (int j = 0; j < 4; ++j) {
            float2 cs = lft[idx];           // wave-uniform broadcast
            xr[j] = fmaf(qv, cs.x, xr[j]);
            xi[j] = fmaf(-qv, cs.y, xi[j]); // e^{-i theta}
            idx = (idx + l) & LMASK;        // (m0+j)*l mod 4096
        }
        base = (base + m0) & LMASK;
    }

    float2* xo = Xp + ((((size_t)ls * NB + b) * NH + h) * NE + i) * NM + m0;
    #pragma unroll
    for (int j = 0; j < 4; ++j) xo[j] = make_float2(xr[j], xi[j]);
}

// Stage 2: complex channel mix per (h,m): OF[b,m,h*64+o] = scale * sum_i X[b,h,i,m]*W[h,i,o,m]
// grid (4 = og, NH, NB), block 256: m = tx&63, osub = tx>>6 (4 outputs each)
__global__ __launch_bounds__(256) void k_stage2(const float* __restrict__ w1,
                                                const float* __restrict__ w2,
                                                const float2* __restrict__ Xp,
                                                float2* __restrict__ OF) {
    const int og = blockIdx.x;              // 0..3
    const int h  = blockIdx.y;
    const int b  = blockIdx.z;
    const int m    = threadIdx.x & 63;
    const int osub = threadIdx.x >> 6;      // 0..3
    const int o0 = og * 16 + osub * 4;

    float re[4] = {0.f,0.f,0.f,0.f}, im[4] = {0.f,0.f,0.f,0.f};

    const float2* x0 = Xp + (((size_t)b * NH + h) * NE) * NM + m;           // ls=0
    const float2* x1 = Xp + ((((size_t)NB + b) * NH + h) * NE) * NM + m;    // ls=1
    const float* w1p = w1 + (size_t)h * NE * NE * NM + (size_t)o0 * NM + m;
    const float* w2p = w2 + (size_t)h * NE * NE * NM + (size_t)o0 * NM + m;

    for (int i = 0; i < NE; ++i) {
        float2 a = x0[(size_t)i * NM];
        float2 c = x1[(size_t)i * NM];
        float xr = a.x + c.x, xi = a.y + c.y;
        #pragma unroll
        for (int oo = 0; oo < 4; ++oo) {
            float wr = w1p[(size_t)i * NE * NM + oo * NM];
            float wi = w2p[(size_t)i * NE * NM + oo * NM];
            re[oo] = fmaf(xr, wr, fmaf(-xi, wi, re[oo]));
            im[oo] = fmaf(xr, wi, fmaf( xi, wr, im[oo]));
        }
    }

    const float s = (m == 0 ? 1.0f : 2.0f) / (float)LN;  // irfft fold: (2-delta_m0)/L
    float2* op = OF + ((size_t)b * NM + m) * NC + h * 64 + o0;
    #pragma unroll
    for (int oo = 0; oo < 4; ++oo) op[oo] = make_float2(re[oo] * s, im[oo] * s);
}

// Stage 3: partial inverse DFT. grid (256 = l-chunks of 16, NB), block 512 (one channel each).
__global__ __launch_bounds__(512) void k_stage3(const float2* __restrict__ OF,
                                                const float2* __restrict__ ftg,
                                                float* __restrict__ out) {
    __shared__ float2 lft[LN];
    for (int j = threadIdx.x; j < LN; j += 512) lft[j] = ftg[j];
    __syncthreads();

    const int l0 = blockIdx.x * 16;
    const int b  = blockIdx.y;
    const int c  = threadIdx.x;

    float acc[16];
    #pragma unroll
    for (int t = 0; t < 16; ++t) acc[t] = 0.f;

    const float2* ofp = OF + (size_t)b * NM * NC + c;
    for (int m = 0; m < NM; ++m) {
        float2 of = ofp[(size_t)m * NC];
        int idx = (m * l0) & LMASK;
        #pragma unroll
        for (int t = 0; t < 16; ++t) {
            float2 cs = lft[idx];           // wave-uniform broadcast
            acc[t] = fmaf(of.x, cs.x, fmaf(-of.y, cs.y, acc[t])); // Re(OF * e^{+i theta})
            idx = (idx + m) & LMASK;
        }
    }

    float* op = out + ((size_t)b * LN + l0) * NC + c;
    #pragma unroll
    for (int t = 0; t < 16; ++t) op[(size_t)t * NC] = acc[t];
}

extern "C" void kernel_launch(void* const* d_in, const int* in_sizes, int n_in,
                              void* d_out, int out_size, void* d_ws, size_t ws_size,
                              hipStream_t stream) {
    const float* q  = (const float*)d_in[0];
    // d_in[1] (k) and d_in[2] (v) are unused by the reference
    const float* w1 = (const float*)d_in[3];
    const float* w2 = (const float*)d_in[4];
    float* out = (float*)d_out;
    float* ws  = (float*)d_ws;

    float2* ft = (float2*)(ws + WS_FT);
    float2* Xp = (float2*)(ws + WS_XP);
    float2* OF = (float2*)(ws + WS_OF);

    k_twiddle<<<16, 256, 0, stream>>>(ft);
    k_stage1<<<dim3(4, NH, NB), 512, 0, stream>>>(q, ft, Xp);
    k_stage2<<<dim3(4, NH, NB), 256, 0, stream>>>(w1, w2, Xp, OF);
    k_stage3<<<dim3(256, NB), 512, 0, stream>>>(OF, ft, out);
}

// Round 2
// 172.936 us; speedup vs baseline: 1.7202x; 1.7202x over previous
//
#include <hip/hip_runtime.h>
#include <hip/hip_bf16.h>
#include <math.h>

// Problem constants
#define NB 8
#define LN 4096       // sequence length L
#define NH 8
#define NE 64
#define NC 512        // NH*NE channels
#define NM 64         // modes kept
#define LMASK 4095

typedef short s16x8 __attribute__((ext_vector_type(8)));
typedef float f32x4 __attribute__((ext_vector_type(4)));

// ws layout (in floats):
//  ft  : float2[4096]                 @ 0           (32 KB)
//  OF  : float2[NB][NM][NC]           @ 8192        (2 MB)
//  Egf : bf16[128kc][8mt][64][8]      @ 532480-ish  (1 MB)   A-fragment twiddle table
//  qtf : bf16[8b][8h][128kc][4nt][64][8]            (32 MB)  B-fragment q table
//  Xp  : f32[8ks][8b][8h][64i][128m±]               (16 MB)  partial GEMM outputs
//  Xs  : f32[8b][8h][64i][128m±]                    (2 MB)   ks-summed
#define WS_FT  0
#define WS_OF  8192
#define WS_EGF (8192 + 524288)              // 532480
#define WS_QTF (532480 + 262144)            // 794624
#define WS_XP  (794624 + 8388608)           // 9183232
#define WS_XS  (9183232 + 4194304)          // 13377536

static __device__ __forceinline__ unsigned short bf16bits(float f) {
    __hip_bfloat16 b = __float2bfloat16(f);
    return *reinterpret_cast<unsigned short*>(&b);
}

__global__ void k_twiddle(float2* __restrict__ ft) {
    int j = blockIdx.x * blockDim.x + threadIdx.x;
    if (j < LN) {
        double a = (2.0 * M_PI / (double)LN) * (double)j;
        ft[j] = make_float2((float)cos(a), (float)sin(a));
    }
}

// Twiddle A-fragment table: E[2m][l]=cos(2pi m l/L), E[2m+1][l]=-sin(2pi m l/L)
// Fragment slot s = (kc<<9) | (mt<<6) | lane ; 8 bf16 per slot: k = (lane>>4)*8+j, row = lane&15.
__global__ __launch_bounds__(256) void k_egf(unsigned short* __restrict__ egf) {
    int s = blockIdx.x * 256 + threadIdx.x;      // 0..65535
    int lane = s & 63, mt = (s >> 6) & 7, kc = s >> 9;
    int r = lane & 15, kg = lane >> 4;
    int mpm = mt * 16 + r;
    int m = mpm >> 1, isim = mpm & 1;
    unsigned short v[8];
    #pragma unroll
    for (int j = 0; j < 8; ++j) {
        int l = kc * 32 + kg * 8 + j;
        int tw = (m * l) & LMASK;
        float ang = (6.283185307179586f / 4096.0f) * (float)tw;
        float val = isim ? -__sinf(ang) : __cosf(ang);
        // use precise sinf/cosf for accuracy (one-time table)
        val = isim ? -sinf(ang) : cosf(ang);
        v[j] = bf16bits(val);
    }
    uint4 pk;
    pk.x = (unsigned)v[0] | ((unsigned)v[1] << 16);
    pk.y = (unsigned)v[2] | ((unsigned)v[3] << 16);
    pk.z = (unsigned)v[4] | ((unsigned)v[5] << 16);
    pk.w = (unsigned)v[6] | ((unsigned)v[7] << 16);
    *reinterpret_cast<uint4*>(egf + (size_t)s * 8) = pk;
}

// q -> bf16 B-fragment table. slot s = b<<18 | h<<15 | kc<<8 | nt<<6 | lane.
// Element j of slot: q[b][ l = kc*32 + (lane>>4)*8 + j ][h][ i = nt*16 + (lane&15) ]
__global__ __launch_bounds__(256) void k_qtf(const float* __restrict__ q,
                                             unsigned short* __restrict__ qtf) {
    int s = blockIdx.x * 256 + threadIdx.x;      // 0..2097151
    int lane = s & 63, nt = (s >> 6) & 3, kc = (s >> 8) & 127, h = (s >> 15) & 7, b = s >> 18;
    int i = nt * 16 + (lane & 15);
    int l0 = kc * 32 + (lane >> 4) * 8;
    const float* qp = q + (((size_t)b * LN + l0) * NH + h) * NE + i;
    unsigned short v[8];
    #pragma unroll
    for (int j = 0; j < 8; ++j) v[j] = bf16bits(qp[(size_t)j * NC]);
    uint4 pk;
    pk.x = (unsigned)v[0] | ((unsigned)v[1] << 16);
    pk.y = (unsigned)v[2] | ((unsigned)v[3] << 16);
    pk.z = (unsigned)v[4] | ((unsigned)v[5] << 16);
    pk.w = (unsigned)v[6] | ((unsigned)v[7] << 16);
    *reinterpret_cast<uint4*>(qtf + (size_t)s * 8) = pk;
}

// Stage 1 MFMA: per (ks,h,b): Xp[ks][b][h][i][m±] += E[m±][l] * q[l][i] over l-chunk.
// grid (8 ks, 8 h, 8 b), block 256 = 4 waves. Wave w owns m± quarter [w*32, w*32+32).
// No LDS, no barriers: fragments stream from global (L2) with 2-deep prefetch.
__global__ __launch_bounds__(256, 2) void k_s1(const unsigned short* __restrict__ qtf,
                                               const unsigned short* __restrict__ egf,
                                               float* __restrict__ xp) {
    const int ks = blockIdx.x, h = blockIdx.y, b = blockIdx.z;
    const int tid = threadIdx.x;
    const int w = tid >> 6, lane = tid & 63;
    const int kc0 = ks * 16;

    const unsigned short* qb = qtf + ((((size_t)(b * 8 + h) * 128 + kc0) * 4) * 64 + lane) * 8;
    const unsigned short* eb = egf + (((size_t)kc0 * 8 + w * 2) * 64 + lane) * 8;

    f32x4 acc[2][4] = {};
    s16x8 af[3][2], bf[3][4];

#define S1_LOAD(T, SLOT)                                                          \
    {                                                                             \
        const unsigned short* ep_ = eb + (size_t)(T) * (8 * 64 * 8);              \
        const unsigned short* qp_ = qb + (size_t)(T) * (4 * 64 * 8);              \
        af[SLOT][0] = *reinterpret_cast<const s16x8*>(ep_);                       \
        af[SLOT][1] = *reinterpret_cast<const s16x8*>(ep_ + 64 * 8);              \
        bf[SLOT][0] = *reinterpret_cast<const s16x8*>(qp_);                       \
        bf[SLOT][1] = *reinterpret_cast<const s16x8*>(qp_ + 64 * 8);              \
        bf[SLOT][2] = *reinterpret_cast<const s16x8*>(qp_ + 2 * 64 * 8);          \
        bf[SLOT][3] = *reinterpret_cast<const s16x8*>(qp_ + 3 * 64 * 8);          \
    }

    S1_LOAD(0, 0)
    S1_LOAD(1, 1)

    #pragma unroll
    for (int t = 0; t < 16; ++t) {
        const int slot = t % 3;
        if (t + 2 < 16) { const int ns = (t + 2) % 3; S1_LOAD(t + 2, ns) }
        #pragma unroll
        for (int mi = 0; mi < 2; ++mi)
            #pragma unroll
            for (int ni = 0; ni < 4; ++ni)
                acc[mi][ni] = __builtin_amdgcn_mfma_f32_16x16x32_bf16(
                    af[slot][mi], bf[slot][ni], acc[mi][ni], 0, 0, 0);
    }
#undef S1_LOAD

    // Epilogue: D[row][col]: col = lane&15 (i-local), row = (lane>>4)*4 + reg (m±-local).
    const int r4 = (lane >> 4) * 4, c = lane & 15;
    float* xpb = xp + ((size_t)ks * 64 + b * 8 + h) * 64 * 128;   // [i][128 m±]
    #pragma unroll
    for (int mi = 0; mi < 2; ++mi)
        #pragma unroll
        for (int ni = 0; ni < 4; ++ni) {
            int i  = ni * 16 + c;
            int mb = w * 32 + mi * 16 + r4;
            *reinterpret_cast<f32x4*>(xpb + (size_t)i * 128 + mb) = acc[mi][ni];
        }
}

// Sum the 8 K-split partials.
__global__ __launch_bounds__(256) void k_presum(const float* __restrict__ xp,
                                                float* __restrict__ xs) {
    int e = blockIdx.x * 256 + threadIdx.x;      // 0..524287
    float s = 0.f;
    #pragma unroll
    for (int ks = 0; ks < 8; ++ks) s += xp[(size_t)ks * 524288 + e];
    xs[e] = s;
}

// Stage 2: complex channel mix per (h,m): OF[b,m,h*64+o] = scale * sum_i X[b,h,i,m]*W[h,i,o,m]
// grid (4 og, NH, NB), block 256: m = tx&63, osub = tx>>6 (4 outputs each).
// Reads Xs[b][h][i][m±] (re,im adjacent -> one float2 load).
__global__ __launch_bounds__(256) void k_stage2(const float* __restrict__ w1,
                                                const float* __restrict__ w2,
                                                const float* __restrict__ xs,
                                                float2* __restrict__ OF) {
    const int og = blockIdx.x;              // 0..3
    const int h  = blockIdx.y;
    const int b  = blockIdx.z;
    const int m    = threadIdx.x & 63;
    const int osub = threadIdx.x >> 6;      // 0..3
    const int o0 = og * 16 + osub * 4;

    float re[4] = {0.f,0.f,0.f,0.f}, im[4] = {0.f,0.f,0.f,0.f};

    const float2* xrow = reinterpret_cast<const float2*>(xs + ((size_t)b * 8 + h) * 64 * 128);
    const float* w1p = w1 + (size_t)h * NE * NE * NM + (size_t)o0 * NM + m;
    const float* w2p = w2 + (size_t)h * NE * NE * NM + (size_t)o0 * NM + m;

    for (int i = 0; i < NE; ++i) {
        float2 xv = xrow[(size_t)i * 64 + m];   // (re, im)
        float xr = xv.x, xi = xv.y;
        #pragma unroll
        for (int oo = 0; oo < 4; ++oo) {
            float wr = w1p[(size_t)i * NE * NM + oo * NM];
            float wi = w2p[(size_t)i * NE * NM + oo * NM];
            re[oo] = fmaf(xr, wr, fmaf(-xi, wi, re[oo]));
            im[oo] = fmaf(xr, wi, fmaf( xi, wr, im[oo]));
        }
    }

    const float s = (m == 0 ? 1.0f : 2.0f) / (float)LN;  // irfft fold: (2-delta_m0)/L
    float2* op = OF + ((size_t)b * NM + m) * NC + h * 64 + o0;
    #pragma unroll
    for (int oo = 0; oo < 4; ++oo) op[oo] = make_float2(re[oo] * s, im[oo] * s);
}

// Stage 3: partial inverse DFT. grid (256 = l-chunks of 16, NB), block 512 (one channel each).
__global__ __launch_bounds__(512) void k_stage3(const float2* __restrict__ OF,
                                                const float2* __restrict__ ftg,
                                                float* __restrict__ out) {
    __shared__ float2 lft[LN];
    for (int j = threadIdx.x; j < LN; j += 512) lft[j] = ftg[j];
    __syncthreads();

    const int l0 = blockIdx.x * 16;
    const int b  = blockIdx.y;
    const int c  = threadIdx.x;

    float acc[16];
    #pragma unroll
    for (int t = 0; t < 16; ++t) acc[t] = 0.f;

    const float2* ofp = OF + (size_t)b * NM * NC + c;
    for (int m = 0; m < NM; ++m) {
        float2 of = ofp[(size_t)m * NC];
        int idx = (m * l0) & LMASK;
        #pragma unroll
        for (int t = 0; t < 16; ++t) {
            float2 cs = lft[idx];           // wave-uniform broadcast
            acc[t] = fmaf(of.x, cs.x, fmaf(-of.y, cs.y, acc[t])); // Re(OF * e^{+i theta})
            idx = (idx + m) & LMASK;
        }
    }

    float* op = out + ((size_t)b * LN + l0) * NC + c;
    #pragma unroll
    for (int t = 0; t < 16; ++t) op[(size_t)t * NC] = acc[t];
}

extern "C" void kernel_launch(void* const* d_in, const int* in_sizes, int n_in,
                              void* d_out, int out_size, void* d_ws, size_t ws_size,
                              hipStream_t stream) {
    const float* q  = (const float*)d_in[0];
    // d_in[1] (k) and d_in[2] (v) are unused by the reference
    const float* w1 = (const float*)d_in[3];
    const float* w2 = (const float*)d_in[4];
    float* out = (float*)d_out;
    float* ws  = (float*)d_ws;

    float2*         ft  = (float2*)(ws + WS_FT);
    float2*         OF  = (float2*)(ws + WS_OF);
    unsigned short* egf = (unsigned short*)(ws + WS_EGF);
    unsigned short* qtf = (unsigned short*)(ws + WS_QTF);
    float*          xp  = ws + WS_XP;
    float*          xs  = ws + WS_XS;

    k_twiddle<<<16, 256, 0, stream>>>(ft);
    k_egf<<<256, 256, 0, stream>>>(egf);
    k_qtf<<<8192, 256, 0, stream>>>(q, qtf);
    k_s1<<<dim3(8, NH, NB), 256, 0, stream>>>(qtf, egf, xp);
    k_presum<<<2048, 256, 0, stream>>>(xp, xs);
    k_stage2<<<dim3(4, NH, NB), 256, 0, stream>>>(w1, w2, xs, OF);
    k_stage3<<<dim3(256, NB), 512, 0, stream>>>(OF, ft, out);
}

// Round 3
// 77.778 us; speedup vs baseline: 3.8249x; 2.2235x over previous
//
#include <hip/hip_runtime.h>
#include <hip/hip_bf16.h>
#include <math.h>

// Problem constants
#define NB 8
#define LN 4096       // sequence length L
#define NH 8
#define NE 64
#define NC 512        // NH*NE channels
#define NM 64         // modes kept
#define LMASK 4095

typedef short s16x8 __attribute__((ext_vector_type(8)));
typedef float f32x4 __attribute__((ext_vector_type(4)));

// ws layout (in floats):
//  egf : bf16[128kc][8mt][64][8]            @ 0         (1 MB)  fwd twiddle A-fragments
//  qtf : bf16[8b][8h][128kc][4nt][64][8]    @ 262144    (32 MB) q B-fragments
//  xp  : f32[8ks][8b][8h][64i][128m±]       @ 8650752   (16 MB) partial fwd GEMM outputs
//  xs  : f32[8b][8h][64i][128m±]            @ 12845056  (2 MB)  ks-summed spectrum
//  gf  : bf16[8b][4kk][32ct][64][8]         @ 13369344  (1 MB)  mixed-spectrum A-fragments (G)
//  tf  : bf16[4kk][256lt][64][8]            @ 13631488  (1 MB)  inv twiddle B-fragments (T)
#define WS_EGF 0
#define WS_QTF 262144
#define WS_XP  8650752
#define WS_XS  12845056
#define WS_GF  13369344
#define WS_TF  13631488

static __device__ __forceinline__ unsigned short bf16bits(float f) {
    __hip_bfloat16 b = __float2bfloat16(f);
    return *reinterpret_cast<unsigned short*>(&b);
}

// Fwd twiddle A-fragment table: E[2m][l]=cos(2pi m l/L), E[2m+1][l]=-sin(2pi m l/L)
// slot s = (kc<<9)|(mt<<6)|lane ; elem j: k = (lane>>4)*8+j (l-local), row = lane&15 (m±-local).
__global__ __launch_bounds__(256) void k_egf(unsigned short* __restrict__ egf) {
    int s = blockIdx.x * 256 + threadIdx.x;      // 0..65535
    int lane = s & 63, mt = (s >> 6) & 7, kc = s >> 9;
    int r = lane & 15, kg = lane >> 4;
    int mpm = mt * 16 + r;
    int m = mpm >> 1, isim = mpm & 1;
    unsigned short v[8];
    #pragma unroll
    for (int j = 0; j < 8; ++j) {
        int l = kc * 32 + kg * 8 + j;
        int tw = (m * l) & LMASK;
        float ang = (6.283185307179586f / 4096.0f) * (float)tw;
        float val = isim ? -sinf(ang) : cosf(ang);
        v[j] = bf16bits(val);
    }
    uint4 pk;
    pk.x = (unsigned)v[0] | ((unsigned)v[1] << 16);
    pk.y = (unsigned)v[2] | ((unsigned)v[3] << 16);
    pk.z = (unsigned)v[4] | ((unsigned)v[5] << 16);
    pk.w = (unsigned)v[6] | ((unsigned)v[7] << 16);
    *reinterpret_cast<uint4*>(egf + (size_t)s * 8) = pk;
}

// Inv twiddle B-fragment table: T[l][2m]=cos(2pi m l/L), T[l][2m+1]=sin(2pi m l/L)
// slot s = (kk<<14)|(lt<<6)|lane ; elem j: mp = kk*32+(lane>>4)*8+j (K), col l = lt*16+(lane&15).
__global__ __launch_bounds__(256) void k_tif(unsigned short* __restrict__ tfp) {
    int s = blockIdx.x * 256 + threadIdx.x;      // 0..65535
    int lane = s & 63, lt = (s >> 6) & 255, kk = s >> 14;
    int l = lt * 16 + (lane & 15);
    int khi = (lane >> 4) * 8;
    unsigned short v[8];
    #pragma unroll
    for (int j = 0; j < 8; ++j) {
        int mp = kk * 32 + khi + j;
        int m = mp >> 1;
        int tw = (m * l) & LMASK;
        float ang = (6.283185307179586f / 4096.0f) * (float)tw;
        float val = (mp & 1) ? sinf(ang) : cosf(ang);
        v[j] = bf16bits(val);
    }
    uint4 pk;
    pk.x = (unsigned)v[0] | ((unsigned)v[1] << 16);
    pk.y = (unsigned)v[2] | ((unsigned)v[3] << 16);
    pk.z = (unsigned)v[4] | ((unsigned)v[5] << 16);
    pk.w = (unsigned)v[6] | ((unsigned)v[7] << 16);
    *reinterpret_cast<uint4*>(tfp + (size_t)s * 8) = pk;
}

// q -> bf16 B-fragment table. slot s = b<<18 | h<<15 | kc<<8 | nt<<6 | lane.
// Element j of slot: q[b][ l = kc*32 + (lane>>4)*8 + j ][h][ i = nt*16 + (lane&15) ]
__global__ __launch_bounds__(256) void k_qtf(const float* __restrict__ q,
                                             unsigned short* __restrict__ qtf) {
    int s = blockIdx.x * 256 + threadIdx.x;      // 0..2097151
    int lane = s & 63, nt = (s >> 6) & 3, kc = (s >> 8) & 127, h = (s >> 15) & 7, b = s >> 18;
    int i = nt * 16 + (lane & 15);
    int l0 = kc * 32 + (lane >> 4) * 8;
    const float* qp = q + (((size_t)b * LN + l0) * NH + h) * NE + i;
    unsigned short v[8];
    #pragma unroll
    for (int j = 0; j < 8; ++j) v[j] = bf16bits(qp[(size_t)j * NC]);
    uint4 pk;
    pk.x = (unsigned)v[0] | ((unsigned)v[1] << 16);
    pk.y = (unsigned)v[2] | ((unsigned)v[3] << 16);
    pk.z = (unsigned)v[4] | ((unsigned)v[5] << 16);
    pk.w = (unsigned)v[6] | ((unsigned)v[7] << 16);
    *reinterpret_cast<uint4*>(qtf + (size_t)s * 8) = pk;
}

// Stage 1 MFMA: per (ks,h,b): Xp[ks][b][h][i][m±] = E[m±][l] * q[l][i] over l-chunk.
// grid (8 ks, 8 h, 8 b), block 256 = 4 waves. Wave w owns m± quarter [w*32, w*32+32).
// No LDS, no barriers: fragments stream from global (L2) with 2-deep prefetch.
__global__ __launch_bounds__(256, 2) void k_s1(const unsigned short* __restrict__ qtf,
                                               const unsigned short* __restrict__ egf,
                                               float* __restrict__ xp) {
    const int ks = blockIdx.x, h = blockIdx.y, b = blockIdx.z;
    const int tid = threadIdx.x;
    const int w = tid >> 6, lane = tid & 63;
    const int kc0 = ks * 16;

    const unsigned short* qb = qtf + ((((size_t)(b * 8 + h) * 128 + kc0) * 4) * 64 + lane) * 8;
    const unsigned short* eb = egf + (((size_t)kc0 * 8 + w * 2) * 64 + lane) * 8;

    f32x4 acc[2][4] = {};
    s16x8 af[3][2], bf[3][4];

#define S1_LOAD(T, SLOT)                                                          \
    {                                                                             \
        const unsigned short* ep_ = eb + (size_t)(T) * (8 * 64 * 8);              \
        const unsigned short* qp_ = qb + (size_t)(T) * (4 * 64 * 8);              \
        af[SLOT][0] = *reinterpret_cast<const s16x8*>(ep_);                       \
        af[SLOT][1] = *reinterpret_cast<const s16x8*>(ep_ + 64 * 8);              \
        bf[SLOT][0] = *reinterpret_cast<const s16x8*>(qp_);                       \
        bf[SLOT][1] = *reinterpret_cast<const s16x8*>(qp_ + 64 * 8);              \
        bf[SLOT][2] = *reinterpret_cast<const s16x8*>(qp_ + 2 * 64 * 8);          \
        bf[SLOT][3] = *reinterpret_cast<const s16x8*>(qp_ + 3 * 64 * 8);          \
    }

    S1_LOAD(0, 0)
    S1_LOAD(1, 1)

    #pragma unroll
    for (int t = 0; t < 16; ++t) {
        const int slot = t % 3;
        if (t + 2 < 16) { const int ns = (t + 2) % 3; S1_LOAD(t + 2, ns) }
        #pragma unroll
        for (int mi = 0; mi < 2; ++mi)
            #pragma unroll
            for (int ni = 0; ni < 4; ++ni)
                acc[mi][ni] = __builtin_amdgcn_mfma_f32_16x16x32_bf16(
                    af[slot][mi], bf[slot][ni], acc[mi][ni], 0, 0, 0);
    }
#undef S1_LOAD

    // Epilogue: D[row][col]: col = lane&15 (i-local), row = (lane>>4)*4 + reg (m±-local).
    const int r4 = (lane >> 4) * 4, c = lane & 15;
    float* xpb = xp + ((size_t)ks * 64 + b * 8 + h) * 64 * 128;   // [i][128 m±]
    #pragma unroll
    for (int mi = 0; mi < 2; ++mi)
        #pragma unroll
        for (int ni = 0; ni < 4; ++ni) {
            int i  = ni * 16 + c;
            int mb = w * 32 + mi * 16 + r4;
            *reinterpret_cast<f32x4*>(xpb + (size_t)i * 128 + mb) = acc[mi][ni];
        }
}

// Sum the 8 K-split partials.
__global__ __launch_bounds__(256) void k_presum(const float* __restrict__ xp,
                                                float* __restrict__ xs) {
    int e = blockIdx.x * 256 + threadIdx.x;      // 0..524287
    float s = 0.f;
    #pragma unroll
    for (int ks = 0; ks < 8; ++ks) s += xp[(size_t)ks * 524288 + e];
    xs[e] = s;
}

// Stage 2: complex channel mix per (h,m); writes G = [s*Re ; -s*Im] directly as bf16
// A-fragments for the inverse GEMM. grid (4 og, NH, NB), block 256: m = tx&63, osub = tx>>6.
__global__ __launch_bounds__(256) void k_stage2(const float* __restrict__ w1,
                                                const float* __restrict__ w2,
                                                const float* __restrict__ xs,
                                                unsigned short* __restrict__ gf) {
    const int og = blockIdx.x;              // 0..3
    const int h  = blockIdx.y;
    const int b  = blockIdx.z;
    const int m    = threadIdx.x & 63;
    const int osub = threadIdx.x >> 6;      // 0..3
    const int o0 = og * 16 + osub * 4;

    float re[4] = {0.f,0.f,0.f,0.f}, im[4] = {0.f,0.f,0.f,0.f};

    const float2* xrow = reinterpret_cast<const float2*>(xs + ((size_t)b * 8 + h) * 64 * 128);
    const float* w1p = w1 + (size_t)h * NE * NE * NM + (size_t)o0 * NM + m;
    const float* w2p = w2 + (size_t)h * NE * NE * NM + (size_t)o0 * NM + m;

    for (int i = 0; i < NE; ++i) {
        float2 xv = xrow[(size_t)i * 64 + m];   // (re, im)
        float xr = xv.x, xi = xv.y;
        #pragma unroll
        for (int oo = 0; oo < 4; ++oo) {
            float wr = w1p[(size_t)i * NE * NM + oo * NM];
            float wi = w2p[(size_t)i * NE * NM + oo * NM];
            re[oo] = fmaf(xr, wr, fmaf(-xi, wi, re[oo]));
            im[oo] = fmaf(xr, wi, fmaf( xi, wr, im[oo]));
        }
    }

    const float s = (m == 0 ? 1.0f : 2.0f) / (float)LN;  // irfft fold: (2-delta_m0)/L
    // G[2m][c] = s*re, G[2m+1][c] = -s*im, written into A-fragment layout:
    // slot = ((b*4 + (m>>4))*32 + (c>>4))*64 + ((m&15)>>2)*16 + (c&15), elems ((m&3)<<1)+{0,1}
    const int kk  = m >> 4;
    const int khi = ((m & 15) >> 2) * 16;
    const int jj  = (m & 3) << 1;
    #pragma unroll
    for (int oo = 0; oo < 4; ++oo) {
        int c = h * 64 + o0 + oo;
        size_t slot = (((size_t)b * 4 + kk) * 32 + (c >> 4)) * 64 + khi + (c & 15);
        unsigned int pk = (unsigned)bf16bits(re[oo] * s) | ((unsigned)bf16bits(-im[oo] * s) << 16);
        *reinterpret_cast<unsigned int*>(gf + slot * 8 + jj) = pk;
    }
}

// Stage 3 MFMA: per b: out[l][c] = sum_mp T[l][mp] * G[mp][c].  M=c(128/block), N=l(64/block), K=128.
// grid (64 lb, 4 cb, 8 b), block 256 = 4 waves; wave w owns c-quarter [w*32, w*32+32).
// Zero LDS / zero barriers; both operand tables stream from L2.
__global__ __launch_bounds__(256, 2) void k_s3(const unsigned short* __restrict__ gf,
                                               const unsigned short* __restrict__ tfp,
                                               float* __restrict__ out) {
    const int lb = blockIdx.x;   // l base = lb*64
    const int cb = blockIdx.y;   // c base = cb*128
    const int b  = blockIdx.z;
    const int tid = threadIdx.x;
    const int w = tid >> 6, lane = tid & 63;

    const unsigned short* ga = gf + ((((size_t)b * 4) * 32 + cb * 8 + w * 2) * 64 + lane) * 8;
    const unsigned short* tb = tfp + (((size_t)lb * 4) * 64 + lane) * 8;

    f32x4 acc[2][4] = {};
    s16x8 af[3][2], bf[3][4];

#define S3_LOAD(T, SLOT)                                                          \
    {                                                                             \
        const unsigned short* gp_ = ga + (size_t)(T) * (32 * 64 * 8);             \
        const unsigned short* tp_ = tb + (size_t)(T) * (256 * 64 * 8);            \
        af[SLOT][0] = *reinterpret_cast<const s16x8*>(gp_);                       \
        af[SLOT][1] = *reinterpret_cast<const s16x8*>(gp_ + 64 * 8);              \
        bf[SLOT][0] = *reinterpret_cast<const s16x8*>(tp_);                       \
        bf[SLOT][1] = *reinterpret_cast<const s16x8*>(tp_ + 64 * 8);              \
        bf[SLOT][2] = *reinterpret_cast<const s16x8*>(tp_ + 2 * 64 * 8);          \
        bf[SLOT][3] = *reinterpret_cast<const s16x8*>(tp_ + 3 * 64 * 8);          \
    }

    S3_LOAD(0, 0)
    S3_LOAD(1, 1)

    #pragma unroll
    for (int t = 0; t < 4; ++t) {
        const int slot = t % 3;
        if (t + 2 < 4) { const int ns = (t + 2) % 3; S3_LOAD(t + 2, ns) }
        #pragma unroll
        for (int mi = 0; mi < 2; ++mi)
            #pragma unroll
            for (int ni = 0; ni < 4; ++ni)
                acc[mi][ni] = __builtin_amdgcn_mfma_f32_16x16x32_bf16(
                    af[slot][mi], bf[slot][ni], acc[mi][ni], 0, 0, 0);
    }
#undef S3_LOAD

    // D[row=c_local][col=l_local]; f32x4 regs span 4 consecutive c.
    const int c0 = cb * 128 + w * 32 + (lane >> 4) * 4;
    const int l0 = lb * 64 + (lane & 15);
    #pragma unroll
    for (int mi = 0; mi < 2; ++mi)
        #pragma unroll
        for (int ni = 0; ni < 4; ++ni) {
            float* op = out + ((size_t)b * LN + l0 + ni * 16) * NC + c0 + mi * 16;
            *reinterpret_cast<f32x4*>(op) = acc[mi][ni];
        }
}

extern "C" void kernel_launch(void* const* d_in, const int* in_sizes, int n_in,
                              void* d_out, int out_size, void* d_ws, size_t ws_size,
                              hipStream_t stream) {
    const float* q  = (const float*)d_in[0];
    // d_in[1] (k) and d_in[2] (v) are unused by the reference
    const float* w1 = (const float*)d_in[3];
    const float* w2 = (const float*)d_in[4];
    float* out = (float*)d_out;
    float* ws  = (float*)d_ws;

    unsigned short* egf = (unsigned short*)(ws + WS_EGF);
    unsigned short* qtf = (unsigned short*)(ws + WS_QTF);
    float*          xp  = ws + WS_XP;
    float*          xs  = ws + WS_XS;
    unsigned short* gf  = (unsigned short*)(ws + WS_GF);
    unsigned short* tfp = (unsigned short*)(ws + WS_TF);

    k_egf<<<256, 256, 0, stream>>>(egf);
    k_tif<<<256, 256, 0, stream>>>(tfp);
    k_qtf<<<8192, 256, 0, stream>>>(q, qtf);
    k_s1<<<dim3(8, NH, NB), 256, 0, stream>>>(qtf, egf, xp);
    k_presum<<<2048, 256, 0, stream>>>(xp, xs);
    k_stage2<<<dim3(4, NH, NB), 256, 0, stream>>>(w1, w2, xs, gf);
    k_s3<<<dim3(64, 4, NB), 256, 0, stream>>>(gf, tfp, out);
}